// Round 7
// baseline (882.455 us; speedup 1.0000x reference)
//
#include <hip/hip_runtime.h>
#include <hip/hip_bf16.h>

typedef _Float16 f16x8 __attribute__((ext_vector_type(8)));
typedef _Float16 f16x4 __attribute__((ext_vector_type(4)));
typedef float f32x4 __attribute__((ext_vector_type(4)));

#define B_   16
#define NL   256
#define NP   2048
#define NH   8
#define PSPLIT 4
#define PCHUNK (NP / PSPLIT)   // 512

static __device__ __forceinline__ f32x4 mfma16(f16x8 a, f16x8 b, f32x4 c) {
  return __builtin_amdgcn_mfma_f32_16x16x32_f16(a, b, c, 0, 0, 0);
}

// ---------------- projection: x[b][n][64] @ W[64][512] + bias, relu ----------------
__global__ __launch_bounds__(256) void proj_kernel(
    const float* __restrict__ x, const float* __restrict__ W, const float* __restrict__ bias,
    _Float16* __restrict__ outA, _Float16* __restrict__ outB, int N, int mode)
{
  __shared__ float xt[64][68];
  const int t = threadIdx.x;
  const int n0 = blockIdx.x * 64;
  const int h  = blockIdx.y;
  const int b  = blockIdx.z;

  const float* xp = x + ((size_t)b * N + n0) * 64;
#pragma unroll
  for (int i = 0; i < 4; ++i) {
    int flat = (i * 256 + t) * 4;
    f32x4 v = *(const f32x4*)(xp + flat);
    *(f32x4*)&xt[flat >> 6][flat & 63] = v;
  }
  __syncthreads();

  const int nb = (t >> 4) * 4;
  const int db = (t & 15) * 4;

  float acc[4][4];
#pragma unroll
  for (int i = 0; i < 4; ++i)
#pragma unroll
    for (int j = 0; j < 4; ++j) acc[i][j] = bias[h * 64 + db + j];

  const float* wp = W + h * 64 + db;
#pragma unroll 8
  for (int k = 0; k < 64; ++k) {
    f32x4 wq = *(const f32x4*)(wp + (size_t)k * 512);
    float a0 = xt[nb + 0][k], a1 = xt[nb + 1][k], a2 = xt[nb + 2][k], a3 = xt[nb + 3][k];
#pragma unroll
    for (int j = 0; j < 4; ++j) {
      acc[0][j] += a0 * wq[j];
      acc[1][j] += a1 * wq[j];
      acc[2][j] += a2 * wq[j];
      acc[3][j] += a3 * wq[j];
    }
  }

  if (mode == 0) {
#pragma unroll
    for (int i = 0; i < 4; ++i) {
      f16x4 hv, lv;
#pragma unroll
      for (int j = 0; j < 4; ++j) {
        float v = fmaxf(acc[i][j], 0.f);
        _Float16 hi = (_Float16)v;
        hv[j] = hi;
        lv[j] = (_Float16)((v - (float)hi) * 2048.0f);
      }
      size_t idx = (((size_t)b * NH + h) * N + n0 + nb + i) * 64 + db;
      *(f16x4*)(outA + idx) = hv;
      *(f16x4*)(outB + idx) = lv;
    }
  } else {
#pragma unroll
    for (int j = 0; j < 4; ++j) {
      f16x4 tv;
#pragma unroll
      for (int i = 0; i < 4; ++i) tv[i] = (_Float16)fmaxf(acc[i][j], 0.f);
      size_t idx = (((size_t)b * NH + h) * 64 + db + j) * N + n0 + nb;
      *(f16x4*)(outA + idx) = tv;
    }
  }
}

// QK fragment set for one 64-p tile (16 b128 regs)
struct QkFr { f16x8 h0[4], h1[4], l0[4], l1[4]; };

// ---------------- flash pass: 4 heads/block, reg-prefetched QK operands ----------------
// grid: x = sp + PSPLIT*b (64), y = lt (16), z = hg (2)
__global__ __launch_bounds__(256) void flash_l3_kernel(
    const _Float16* __restrict__ l1h, const _Float16* __restrict__ l1l,
    const _Float16* __restrict__ p1h, const _Float16* __restrict__ p1l,
    const _Float16* __restrict__ p2t, const float* __restrict__ dist,
    float* __restrict__ l3p, float* __restrict__ mpart, float* __restrict__ spart)
{
  const int sb = blockIdx.x;
  const int sp = sb & (PSPLIT - 1);
  const int b  = sb >> 2;
  const int lt = blockIdx.y;
  const int hg = blockIdx.z;
  const int t  = threadIdx.x;
  const int w    = t >> 6;            // wave 0..3
  const int h    = hg * 4 + w;
  const int lane = t & 63;
  const int g = lane >> 4, c = lane & 15;
  const int l0 = lt * 16;
  const int bh = b * NH + h;
  const int NT = PCHUNK / 64;         // 8

  __shared__ float dT[2][64][20];     // [buf][p-local][l-local] raw d
  __shared__ float rT[2][64][20];     // [buf][p-local][l-local] 0.125/d
  __shared__ _Float16 P[4][16][72];   // per-wave scratch

  const size_t l1off = ((size_t)bh * NL + l0 + c) * 64;
  f16x8 aLh[2], aLl[2];
  aLh[0] = *(const f16x8*)(l1h + l1off + g * 8);
  aLh[1] = *(const f16x8*)(l1h + l1off + 32 + g * 8);
  aLl[0] = *(const f16x8*)(l1l + l1off + g * 8);
  aLl[1] = *(const f16x8*)(l1l + l1off + 32 + g * 8);

  f32x4 accO[4];
#pragma unroll
  for (int dt = 0; dt < 4; ++dt) accO[dt] = (f32x4){0.f, 0.f, 0.f, 0.f};
  float m_r[4] = {-INFINITY, -INFINITY, -INFINITY, -INFINITY};
  float s_r[4] = {0.f, 0.f, 0.f, 0.f};

  const float* dbase = dist + ((size_t)b * NL + l0) * NP + sp * PCHUNK;
  const _Float16* p1hb = p1h + ((size_t)bh * NP + sp * PCHUNK) * 64;
  const _Float16* p1lb = p1l + ((size_t)bh * NP + sp * PCHUNK) * 64;
  const _Float16* p2tb = p2t + (size_t)bh * 64 * NP + sp * PCHUNK;
  const float fh = (float)h, fh3 = fh + 3.0f;

  const int dl_p = t & 63;            // coop stage: p-local; wave w stages l rows 4w..4w+3

  // prologue: stage dist tile 0 and load QK fragments for tile 0
#pragma unroll
  for (int i = 0; i < 4; ++i) {
    float dv = dbase[(size_t)(w * 4 + i) * NP + dl_p];
    dT[0][dl_p][w * 4 + i] = dv;
    rT[0][dl_p][w * 4 + i] = 0.125f * __builtin_amdgcn_rcpf(dv);
  }

  QkFr frA, frB;
#define LOAD_FR(FR, PB) do {                                            \
    _Pragma("unroll")                                                   \
    for (int s_ = 0; s_ < 4; ++s_) {                                    \
      const _Float16* ph_ = p1hb + (size_t)((PB) + s_ * 16 + c) * 64;   \
      const _Float16* pl_ = p1lb + (size_t)((PB) + s_ * 16 + c) * 64;   \
      FR.h0[s_] = *(const f16x8*)(ph_ + g * 8);                         \
      FR.h1[s_] = *(const f16x8*)(ph_ + 32 + g * 8);                    \
      FR.l0[s_] = *(const f16x8*)(pl_ + g * 8);                         \
      FR.l1[s_] = *(const f16x8*)(pl_ + 32 + g * 8);                    \
    }                                                                   \
  } while (0)

  LOAD_FR(frA, 0);

#define QK_STEP(CURF, NXTF, IT) do {                                    \
    const int P0_ = (IT) * 64;                                          \
    const int cur_ = (IT) & 1;                                          \
    __syncthreads();                                                    \
    float nv_[4];                                                       \
    if ((IT) + 1 < NT) {                                                \
      _Pragma("unroll")                                                 \
      for (int i_ = 0; i_ < 4; ++i_)                                    \
        nv_[i_] = dbase[(size_t)(w * 4 + i_) * NP + P0_ + 64 + dl_p];   \
      LOAD_FR(NXTF, P0_ + 64);                                          \
    }                                                                   \
    float mev_[4][4];                                                   \
    float cmax_[4] = {-INFINITY, -INFINITY, -INFINITY, -INFINITY};      \
    _Pragma("unroll")                                                   \
    for (int s_ = 0; s_ < 4; ++s_) {                                    \
      f32x4 e_  = (f32x4){0.f, 0.f, 0.f, 0.f};                          \
      f32x4 ec_ = (f32x4){0.f, 0.f, 0.f, 0.f};                          \
      __builtin_amdgcn_s_setprio(1);                                    \
      e_  = mfma16(aLh[0], CURF.h0[s_], e_);                            \
      e_  = mfma16(aLh[1], CURF.h1[s_], e_);                            \
      ec_ = mfma16(aLh[0], CURF.l0[s_], ec_);                           \
      ec_ = mfma16(aLh[1], CURF.l1[s_], ec_);                           \
      ec_ = mfma16(aLl[0], CURF.h0[s_], ec_);                           \
      ec_ = mfma16(aLl[1], CURF.h1[s_], ec_);                           \
      __builtin_amdgcn_s_setprio(0);                                    \
      f32x4 dq_ = *(const f32x4*)&dT[cur_][s_ * 16 + c][g * 4];         \
      f32x4 rq_ = *(const f32x4*)&rT[cur_][s_ * 16 + c][g * 4];         \
      _Pragma("unroll")                                                 \
      for (int r_ = 0; r_ < 4; ++r_) {                                  \
        float dv_ = dq_[r_];                                            \
        bool cd_ = (h < 7) ? (dv_ > fh && dv_ <= fh3) : (dv_ > 7.0f);   \
        float rm_ = cd_ ? rq_[r_] : 0.0f;                               \
        float ev_ = fmaf(ec_[r_], 1.0f / 2048.0f, e_[r_]);              \
        float m_ = ev_ * rm_;                                           \
        mev_[s_][r_] = m_;                                              \
        cmax_[r_] = fmaxf(cmax_[r_], m_);                               \
      }                                                                 \
    }                                                                   \
    _Pragma("unroll")                                                   \
    for (int mk_ = 1; mk_ < 16; mk_ <<= 1)                              \
      _Pragma("unroll")                                                 \
      for (int r_ = 0; r_ < 4; ++r_)                                    \
        cmax_[r_] = fmaxf(cmax_[r_], __shfl_xor(cmax_[r_], mk_, 64));   \
    _Pragma("unroll")                                                   \
    for (int r_ = 0; r_ < 4; ++r_) {                                    \
      float mn_  = fmaxf(m_r[r_], cmax_[r_]);                           \
      float fac_ = __expf(m_r[r_] - mn_);                               \
      m_r[r_] = mn_;                                                    \
      float ss_ = 0.f;                                                  \
      _Pragma("unroll")                                                 \
      for (int s_ = 0; s_ < 4; ++s_) {                                  \
        float pv_ = __expf(mev_[s_][r_] - mn_);                         \
        ss_ += pv_;                                                     \
        P[w][g * 4 + r_][s_ * 16 + c] = (_Float16)pv_;                  \
      }                                                                 \
      s_r[r_] = s_r[r_] * fac_ + ss_;                                   \
      _Pragma("unroll")                                                 \
      for (int dt_ = 0; dt_ < 4; ++dt_) accO[dt_][r_] *= fac_;          \
    }                                                                   \
    _Pragma("unroll")                                                   \
    for (int kk_ = 0; kk_ < 2; ++kk_) {                                 \
      f16x8 aP_ = *(const f16x8*)&P[w][c][kk_ * 32 + g * 8];            \
      __builtin_amdgcn_s_setprio(1);                                    \
      _Pragma("unroll")                                                 \
      for (int dt_ = 0; dt_ < 4; ++dt_) {                               \
        f16x8 bV_ = *(const f16x8*)(p2tb +                              \
            (size_t)(dt_ * 16 + c) * NP + P0_ + kk_ * 32 + g * 8);      \
        accO[dt_] = mfma16(aP_, bV_, accO[dt_]);                        \
      }                                                                 \
      __builtin_amdgcn_s_setprio(0);                                    \
    }                                                                   \
    if ((IT) + 1 < NT) {                                                \
      _Pragma("unroll")                                                 \
      for (int i_ = 0; i_ < 4; ++i_) {                                  \
        dT[cur_ ^ 1][dl_p][w * 4 + i_] = nv_[i_];                       \
        rT[cur_ ^ 1][dl_p][w * 4 + i_] =                                \
            0.125f * __builtin_amdgcn_rcpf(nv_[i_]);                    \
      }                                                                 \
    }                                                                   \
  } while (0)

  for (int it = 0; it < NT; it += 2) {
    QK_STEP(frA, frB, it);
    QK_STEP(frB, frA, it + 1);
  }
#undef QK_STEP
#undef LOAD_FR

#pragma unroll
  for (int mask = 1; mask < 16; mask <<= 1)
#pragma unroll
    for (int r = 0; r < 4; ++r) s_r[r] += __shfl_xor(s_r[r], mask, 64);

  float* lp = l3p + (size_t)sp * B_ * NL * 512;
#pragma unroll
  for (int dt = 0; dt < 4; ++dt)
#pragma unroll
    for (int r = 0; r < 4; ++r)
      lp[((size_t)b * NL + l0 + g * 4 + r) * 512 + h * 64 + dt * 16 + c] = accO[dt][r];

  if (c == 0) {
#pragma unroll
    for (int r = 0; r < 4; ++r) {
      size_t li = (size_t)sp * B_ * NH * NL + (size_t)bh * NL + l0 + g * 4 + r;
      mpart[li] = m_r[r];
      spart[li] = s_r[r];
    }
  }
}

// ---------------- merge split-P partials; mrow <- LSE = M + ln(S) ----------------
__global__ __launch_bounds__(256) void merge_l3_kernel(
    const float* __restrict__ l3p, const float* __restrict__ mpart, const float* __restrict__ spart,
    float* __restrict__ l3c, float* __restrict__ mrow)
{
  const int row = blockIdx.x * 4 + (threadIdx.x >> 6);
  const int d   = threadIdx.x & 63;
  const int l   = row & (NL - 1);
  const int bh  = row >> 8;
  const int b = bh >> 3, h = bh & 7;
  const size_t srow = (size_t)B_ * NH * NL;

  float mi[PSPLIT], si[PSPLIT];
  float M = -INFINITY;
#pragma unroll
  for (int i = 0; i < PSPLIT; ++i) {
    mi[i] = mpart[(size_t)i * srow + row];
    si[i] = spart[(size_t)i * srow + row];
    M = fmaxf(M, mi[i]);
  }
  const float* lp = l3p + ((size_t)b * NL + l) * 512 + h * 64 + d;
  float S = 0.f, o = 0.f;
#pragma unroll
  for (int i = 0; i < PSPLIT; ++i) {
    float w = __expf(mi[i] - M);
    S += si[i] * w;
    o += lp[(size_t)i * B_ * NL * 512] * w;
  }
  l3c[((size_t)b * NL + l) * 512 + h * 64 + d] = o / S;
  if (d == 0) mrow[row] = M + __logf(S);   // logsumexp
}

// l1 fragment set for one 32-l tile (8 b128 regs)
struct LFr { f16x8 h0[2], h1[2], l0[2], l1[2]; };

// ---------------- pass 2: p3 = att^T @ l2 ; att = exp(m - LSE), reg-prefetched ----------------
// grid: x = b (16), y = pt (128), z = hg (2)
__global__ __launch_bounds__(256) void p3_kernel(
    const _Float16* __restrict__ p1h, const _Float16* __restrict__ p1l,
    const _Float16* __restrict__ l1h, const _Float16* __restrict__ l1l,
    const _Float16* __restrict__ l2t, const float* __restrict__ dist,
    const float* __restrict__ mrow,
    float* __restrict__ p3c)
{
  const int b  = blockIdx.x;
  const int pt = blockIdx.y;
  const int hg = blockIdx.z;
  const int t  = threadIdx.x;
  const int w    = t >> 6;
  const int h    = hg * 4 + w;
  const int lane = t & 63;
  const int g = lane >> 4, c = lane & 15;
  const int p0 = pt * 16;
  const int bh = b * NH + h;
  const int NT = NL / 32;             // 8

  __shared__ float dT[2][32][20];     // [buf][l-local][p-local] raw d
  __shared__ float rT[2][32][20];     // [buf][l-local][p-local] 0.125/d
  __shared__ _Float16 PT[4][16][40];  // per-wave

  const size_t poff = ((size_t)bh * NP + p0 + c) * 64;
  f16x8 aPh[2], aPl[2];
  aPh[0] = *(const f16x8*)(p1h + poff + g * 8);
  aPh[1] = *(const f16x8*)(p1h + poff + 32 + g * 8);
  aPl[0] = *(const f16x8*)(p1l + poff + g * 8);
  aPl[1] = *(const f16x8*)(p1l + poff + 32 + g * 8);

  f32x4 acc[4];
#pragma unroll
  for (int dt = 0; dt < 4; ++dt) acc[dt] = (f32x4){0.f, 0.f, 0.f, 0.f};

  const float* db_ = dist + (size_t)b * NL * NP + p0;
  const _Float16* l1hb = l1h + (size_t)bh * NL * 64;
  const _Float16* l1lb = l1l + (size_t)bh * NL * 64;
  const _Float16* l2tb = l2t + (size_t)bh * 64 * NL;
  const float* mb = mrow + (size_t)bh * NL;
  const float fh = (float)h, fh3 = fh + 3.0f;

  const int dl_l = t >> 4;            // 0..15 ; rows dl_l, dl_l+16
  const int dl_p = t & 15;

  // prologue: stage dist tile 0, load l1 fragments for tile 0
#pragma unroll
  for (int i = 0; i < 2; ++i) {
    float dv = db_[(size_t)(dl_l + 16 * i) * NP + dl_p];
    dT[0][dl_l + 16 * i][dl_p] = dv;
    rT[0][dl_l + 16 * i][dl_p] = 0.125f * __builtin_amdgcn_rcpf(dv);
  }

  LFr frA, frB;
#define LOAD_LFR(FR, LB) do {                                           \
    _Pragma("unroll")                                                   \
    for (int s_ = 0; s_ < 2; ++s_) {                                    \
      const _Float16* lh_ = l1hb + (size_t)((LB) + s_ * 16 + c) * 64;   \
      const _Float16* ll_ = l1lb + (size_t)((LB) + s_ * 16 + c) * 64;   \
      FR.h0[s_] = *(const f16x8*)(lh_ + g * 8);                         \
      FR.h1[s_] = *(const f16x8*)(lh_ + 32 + g * 8);                    \
      FR.l0[s_] = *(const f16x8*)(ll_ + g * 8);                         \
      FR.l1[s_] = *(const f16x8*)(ll_ + 32 + g * 8);                    \
    }                                                                   \
  } while (0)

  LOAD_LFR(frA, 0);

#define P3_STEP(CURF, NXTF, IT) do {                                    \
    const int lc_ = (IT) * 32;                                          \
    const int cur_ = (IT) & 1;                                          \
    __syncthreads();                                                    \
    float nv_[2];                                                       \
    if ((IT) + 1 < NT) {                                                \
      _Pragma("unroll")                                                 \
      for (int i_ = 0; i_ < 2; ++i_)                                    \
        nv_[i_] = db_[(size_t)(lc_ + 32 + dl_l + 16 * i_) * NP + dl_p]; \
      LOAD_LFR(NXTF, lc_ + 32);                                         \
    }                                                                   \
    _Pragma("unroll")                                                   \
    for (int s_ = 0; s_ < 2; ++s_) {                                    \
      const int l_ = lc_ + s_ * 16 + c;                                 \
      f32x4 e_  = (f32x4){0.f, 0.f, 0.f, 0.f};                          \
      f32x4 ec_ = (f32x4){0.f, 0.f, 0.f, 0.f};                          \
      __builtin_amdgcn_s_setprio(1);                                    \
      e_  = mfma16(aPh[0], CURF.h0[s_], e_);                            \
      e_  = mfma16(aPh[1], CURF.h1[s_], e_);                            \
      ec_ = mfma16(aPh[0], CURF.l0[s_], ec_);                           \
      ec_ = mfma16(aPh[1], CURF.l1[s_], ec_);                           \
      ec_ = mfma16(aPl[0], CURF.h0[s_], ec_);                           \
      ec_ = mfma16(aPl[1], CURF.h1[s_], ec_);                           \
      __builtin_amdgcn_s_setprio(0);                                    \
      float lse_ = mb[l_];                                              \
      f32x4 dq_ = *(const f32x4*)&dT[cur_][s_ * 16 + c][g * 4];         \
      f32x4 rq_ = *(const f32x4*)&rT[cur_][s_ * 16 + c][g * 4];         \
      _Pragma("unroll")                                                 \
      for (int r_ = 0; r_ < 4; ++r_) {                                  \
        float dv_ = dq_[r_];                                            \
        bool cd_ = (h < 7) ? (dv_ > fh && dv_ <= fh3) : (dv_ > 7.0f);   \
        float rm_ = cd_ ? rq_[r_] : 0.0f;                               \
        float ev_ = fmaf(ec_[r_], 1.0f / 2048.0f, e_[r_]);              \
        float att_ = __expf(fmaf(ev_, rm_, -lse_));                     \
        PT[w][g * 4 + r_][s_ * 16 + c] = (_Float16)att_;                \
      }                                                                 \
    }                                                                   \
    {                                                                   \
      f16x8 aA_ = *(const f16x8*)&PT[w][c][g * 8];                      \
      __builtin_amdgcn_s_setprio(1);                                    \
      _Pragma("unroll")                                                 \
      for (int dt_ = 0; dt_ < 4; ++dt_) {                               \
        f16x8 bV_ = *(const f16x8*)(l2tb +                              \
            (size_t)(dt_ * 16 + c) * NL + lc_ + g * 8);                 \
        acc[dt_] = mfma16(aA_, bV_, acc[dt_]);                          \
      }                                                                 \
      __builtin_amdgcn_s_setprio(0);                                    \
    }                                                                   \
    if ((IT) + 1 < NT) {                                                \
      _Pragma("unroll")                                                 \
      for (int i_ = 0; i_ < 2; ++i_) {                                  \
        dT[cur_ ^ 1][dl_l + 16 * i_][dl_p] = nv_[i_];                   \
        rT[cur_ ^ 1][dl_l + 16 * i_][dl_p] =                            \
            0.125f * __builtin_amdgcn_rcpf(nv_[i_]);                    \
      }                                                                 \
    }                                                                   \
  } while (0)

  for (int it = 0; it < NT; it += 2) {
    P3_STEP(frA, frB, it);
    P3_STEP(frB, frA, it + 1);
  }
#undef P3_STEP
#undef LOAD_LFR

#pragma unroll
  for (int dt = 0; dt < 4; ++dt)
#pragma unroll
    for (int r = 0; r < 4; ++r)
      p3c[((size_t)b * NP + p0 + g * 4 + r) * 512 + h * 64 + dt * 16 + c] = acc[dt][r];
}

// ---------------- FC chain ----------------
__global__ __launch_bounds__(256) void fc_out_kernel(
    const float* __restrict__ x3c, const float* __restrict__ xbase,
    const float* __restrict__ wA, const float* __restrict__ bA,
    const float* __restrict__ wB, const float* __restrict__ bB,
    float* __restrict__ out, int N, int out_off)
{
  __shared__ float xl[16][520];
  __shared__ float t1[16][68];
  __shared__ float xb[16][68];
  const int t = threadIdx.x;
  const int row0 = blockIdx.x * 16;

  const float* xp = x3c + (size_t)row0 * 512;
#pragma unroll
  for (int i = 0; i < 8; ++i) {
    int flat = (i * 256 + t) * 4;
    f32x4 v = *(const f32x4*)(xp + flat);
    *(f32x4*)&xl[flat >> 9][flat & 511] = v;
  }
  {
    const float* bp = xbase + (size_t)row0 * 64;
    int flat = t * 4;
    f32x4 v = *(const f32x4*)(bp + flat);
    *(f32x4*)&xb[flat >> 6][flat & 63] = v;
  }
  __syncthreads();

  const int r  = t >> 4;
  const int c4 = (t & 15) * 4;

  float acc[4];
#pragma unroll
  for (int j = 0; j < 4; ++j) acc[j] = bA[c4 + j];
  for (int k4 = 0; k4 < 128; ++k4) {
    f32x4 xq = *(const f32x4*)&xl[r][k4 * 4];
#pragma unroll
    for (int kk = 0; kk < 4; ++kk) {
      f32x4 wq = *(const f32x4*)(wA + (size_t)(k4 * 4 + kk) * 64 + c4);
#pragma unroll
      for (int j = 0; j < 4; ++j) acc[j] += xq[kk] * wq[j];
    }
  }
#pragma unroll
  for (int j = 0; j < 4; ++j) t1[r][c4 + j] = acc[j];
  __syncthreads();

  float a2[4];
#pragma unroll
  for (int j = 0; j < 4; ++j) a2[j] = bB[c4 + j];
  for (int k4 = 0; k4 < 32; ++k4) {
    f32x4 xq = (k4 < 16) ? *(const f32x4*)&t1[r][k4 * 4]
                         : *(const f32x4*)&xb[r][k4 * 4 - 64];
#pragma unroll
    for (int kk = 0; kk < 4; ++kk) {
      f32x4 wq = *(const f32x4*)(wB + (size_t)(k4 * 4 + kk) * 64 + c4);
#pragma unroll
      for (int j = 0; j < 4; ++j) a2[j] += xq[kk] * wq[j];
    }
  }
  const int row = row0 + r;
  const int b = row / N, n = row % N;
  f32x4 o;
#pragma unroll
  for (int j = 0; j < 4; ++j) o[j] = fmaxf(a2[j], 0.f);
  *(f32x4*)(out + (((size_t)b * (NL + NP)) + out_off + n) * 64 + c4) = o;
}

extern "C" void kernel_launch(void* const* d_in, const int* in_sizes, int n_in,
                              void* d_out, int out_size, void* d_ws, size_t ws_size,
                              hipStream_t stream)
{
  const float* ligand = (const float*)d_in[0];
  const float* prot   = (const float*)d_in[1];
  const float* dist   = (const float*)d_in[2];
  const float* w_l1   = (const float*)d_in[3];
  const float* b_l1   = (const float*)d_in[4];
  const float* w_l2   = (const float*)d_in[5];
  const float* b_l2   = (const float*)d_in[6];
  const float* w_p1   = (const float*)d_in[7];
  const float* b_p1   = (const float*)d_in[8];
  const float* w_p2   = (const float*)d_in[9];
  const float* b_p2   = (const float*)d_in[10];
  const float* fc11_w = (const float*)d_in[11];
  const float* fc11_b = (const float*)d_in[12];
  const float* fc12_w = (const float*)d_in[13];
  const float* fc12_b = (const float*)d_in[14];
  const float* fc21_w = (const float*)d_in[15];
  const float* fc21_b = (const float*)d_in[16];
  const float* fc22_w = (const float*)d_in[17];
  const float* fc22_b = (const float*)d_in[18];
  float* out = (float*)d_out;

  char* ws = (char*)d_ws;
  size_t off = 0;
  auto alloc = [&](size_t bytes) -> void* {
    void* p = ws + off;
    off += (bytes + 255) & ~(size_t)255;
    return p;
  };
  const size_t L1E = (size_t)B_ * NH * NL * 64;
  const size_t P1E = (size_t)B_ * NH * NP * 64;
  _Float16* l1h = (_Float16*)alloc(L1E * 2);
  _Float16* l1l = (_Float16*)alloc(L1E * 2);
  _Float16* p1h = (_Float16*)alloc(P1E * 2);
  _Float16* p1l = (_Float16*)alloc(P1E * 2);
  _Float16* l2t = (_Float16*)alloc(L1E * 2);
  _Float16* p2t = (_Float16*)alloc(P1E * 2);
  float* mrow  = (float*)alloc((size_t)B_ * NH * NL * 4);
  float* mpart = (float*)alloc((size_t)PSPLIT * B_ * NH * NL * 4);
  float* spart = (float*)alloc((size_t)PSPLIT * B_ * NH * NL * 4);
  float* l3c = (float*)alloc((size_t)B_ * NL * 512 * 4);
  float* p3c = (float*)alloc((size_t)B_ * NP * 512 * 4);
  float* l3p = p3c;   // alias: l3 partials (34 MB) dead before p3 writes p3c

  proj_kernel<<<dim3(NL / 64, NH, B_), 256, 0, stream>>>(ligand, w_l1, b_l1, l1h, l1l, NL, 0);
  proj_kernel<<<dim3(NL / 64, NH, B_), 256, 0, stream>>>(ligand, w_l2, b_l2, l2t, nullptr, NL, 1);
  proj_kernel<<<dim3(NP / 64, NH, B_), 256, 0, stream>>>(prot, w_p1, b_p1, p1h, p1l, NP, 0);
  proj_kernel<<<dim3(NP / 64, NH, B_), 256, 0, stream>>>(prot, w_p2, b_p2, p2t, nullptr, NP, 1);

  flash_l3_kernel<<<dim3(PSPLIT * B_, NL / 16, 2), 256, 0, stream>>>(
      l1h, l1l, p1h, p1l, p2t, dist, l3p, mpart, spart);
  merge_l3_kernel<<<(B_ * NH * NL) / 4, 256, 0, stream>>>(l3p, mpart, spart, l3c, mrow);
  p3_kernel<<<dim3(B_, NP / 16, 2), 256, 0, stream>>>(p1h, p1l, l1h, l1l, l2t, dist,
                                                      mrow, p3c);

  fc_out_kernel<<<(B_ * NL) / 16, 256, 0, stream>>>(l3c, ligand, fc11_w, fc11_b,
                                                    fc12_w, fc12_b, out, NL, 0);
  fc_out_kernel<<<(B_ * NP) / 16, 256, 0, stream>>>(p3c, prot, fc21_w, fc21_b,
                                                    fc22_w, fc22_b, out, NP, NL);
}